// Round 3
// baseline (1610.480 us; speedup 1.0000x reference)
//
#include <hip/hip_runtime.h>
#include <hip/hip_bf16.h>
#include <stdint.h>

typedef unsigned int u32;

// ---------------------------------------------------------------------------
// threefry2x32 (matches jax/_src/prng.py threefry2x32 exactly)
// ---------------------------------------------------------------------------
__host__ __device__ constexpr void tf_block(u32 k0, u32 k1, u32& x0, u32& x1) {
  const u32 ks2 = k0 ^ k1 ^ 0x1BD11BDAu;
  const u32 ks[3] = {k0, k1, ks2};
  const int R[2][4] = {{13, 15, 26, 6}, {17, 29, 16, 24}};
  x0 += k0;
  x1 += k1;
  for (int i = 0; i < 5; ++i) {
    for (int j = 0; j < 4; ++j) {
      const int r = R[i & 1][j];
      x0 += x1;
      x1 = (x1 << r) | (x1 >> (32 - r));
      x1 ^= x0;
    }
    x0 += ks[(i + 1) % 3];
    x1 += ks[(i + 2) % 3] + (u32)(i + 1);
  }
}

struct KeyPair { u32 a, b; };
__host__ __device__ constexpr KeyPair tf_pair(u32 k0, u32 k1, u32 c0, u32 c1) {
  u32 x0 = c0, x1 = c1;
  tf_block(k0, k1, x0, x1);
  return KeyPair{x0, x1};
}

// jax.random.key(42) -> (0,42). partitionable split: dk_i = threefry(key,(0,i))
constexpr KeyPair DK1 = tf_pair(0u, 42u, 0u, 0u);
constexpr KeyPair DK2 = tf_pair(0u, 42u, 0u, 1u);

// partitionable random_bits(32): bits = y0 ^ y1 of threefry(dk, (0, flat_idx));
// uniform<0.5  <=>  MSB(bits)==0
__device__ __forceinline__ bool keep_elem(u32 ka, u32 kb, u32 idx) {
  u32 x0 = 0u, x1 = idx;
  tf_block(ka, kb, x0, x1);
  return ((x0 ^ x1) & 0x80000000u) == 0u;
}

// ---------------------------------------------------------------------------
// edge_index dtype detection: int64 => all odd u32 words (hi) are zero
// ---------------------------------------------------------------------------
__global__ void detect_kernel(const u32* __restrict__ ei, u32* __restrict__ flag) {
  if (threadIdx.x == 0) {
    u32 acc = 0;
    for (int k = 0; k < 32; ++k) acc |= ei[2 * k + 1];
    *flag = (acc == 0u) ? 1u : 0u;
  }
}

__global__ void zero2(float* __restrict__ a, u32* __restrict__ b, int n) {
  const int i = blockIdx.x * blockDim.x + threadIdx.x;
  if (i < n) { a[i] = 0.f; b[i] = 0u; }
}

// histogram: weighted degree (for dis) + in-degree counts (for CSR offsets)
__global__ __launch_bounds__(256) void edge_deg_count(
    const u32* __restrict__ ei, const float* __restrict__ ew,
    float* __restrict__ deg, u32* __restrict__ counts, int E,
    const u32* __restrict__ flag) {
  const int e = blockIdx.x * 256 + threadIdx.x;
  if (e >= E) return;
  const bool is64 = (*flag != 0u);
  const u32 c = is64 ? ei[2 * ((size_t)E + e)] : ei[(size_t)E + e];
  atomicAdd(&deg[c], ew[e]);
  atomicAdd(&counts[c], 1u);
}

// single-block exclusive scan of counts -> offsets (+cursor copy), and dis
__global__ __launch_bounds__(1024) void scan_kernel(
    const u32* __restrict__ counts, u32* __restrict__ offsets,
    u32* __restrict__ cursor, const float* __restrict__ deg,
    float* __restrict__ dis, int N) {
  __shared__ u32 wsum[16];
  __shared__ u32 carry_s;
  const int t = threadIdx.x, lane = t & 63, wv = t >> 6;
  if (t == 0) carry_s = 0u;
  __syncthreads();
  for (int base = 0; base < N; base += 1024) {
    const int i = base + t;
    const u32 v = (i < N) ? counts[i] : 0u;
    u32 inc = v;
#pragma unroll
    for (int off = 1; off < 64; off <<= 1) {
      const u32 tmp = (u32)__shfl_up((int)inc, off, 64);
      if (lane >= off) inc += tmp;
    }
    if (lane == 63) wsum[wv] = inc;
    __syncthreads();
    if (wv == 0) {
      u32 wval = (lane < 16) ? wsum[lane] : 0u;
#pragma unroll
      for (int off = 1; off < 16; off <<= 1) {
        const u32 tmp = (u32)__shfl_up((int)wval, off, 64);
        if (lane >= off) wval += tmp;
      }
      if (lane < 16) wsum[lane] = wval;  // inclusive wave sums
    }
    __syncthreads();
    const u32 c0 = carry_s;
    const u32 wpre = (wv == 0) ? 0u : wsum[wv - 1];
    const u32 excl = c0 + wpre + inc - v;
    if (i < N) { offsets[i] = excl; cursor[i] = excl; }
    __syncthreads();
    if (t == 0) carry_s = c0 + wsum[15];
    __syncthreads();
  }
  if (t == 0) offsets[N] = carry_s;
  for (int i = t; i < N; i += 1024) dis[i] = rsqrtf(deg[i] + 1.0f);
}

// counting-sort scatter: group (src, w) by destination
__global__ __launch_bounds__(256) void scatter_kernel(
    const u32* __restrict__ ei, const float* __restrict__ ew,
    u32* __restrict__ cursor, uint2* __restrict__ srcw, int E,
    const u32* __restrict__ flag) {
  const int e = blockIdx.x * 256 + threadIdx.x;
  if (e >= E) return;
  const bool is64 = (*flag != 0u);
  u32 r, c;
  if (is64) { r = ei[2 * (size_t)e]; c = ei[2 * ((size_t)E + e)]; }
  else      { r = ei[e];             c = ei[(size_t)E + e]; }
  const u32 pos = atomicAdd(&cursor[c], 1u);
  srcw[pos] = make_uint2(r, __float_as_uint(ew[e]));
}

// ---------------------------------------------------------------------------
// hs = dis .* (x @ W)   fp32, W + x tile in LDS
// ---------------------------------------------------------------------------
template <int DOUT>
__global__ __launch_bounds__(256) void gemm_scale(
    const float* __restrict__ x, const float* __restrict__ W,
    const float* __restrict__ dis, float* __restrict__ hs, int N) {
  static_assert(DOUT == 128 || DOUT == 64, "");
  constexpr int ROWS = 64;
  constexpr int CT = DOUT / 32;  // cols per thread
  constexpr int RT = 8;          // rows per thread
  __shared__ float wlds[128 * DOUT];
  __shared__ float xlds[ROWS * 128];

  const int tid = threadIdx.x;
  const int rowbase = blockIdx.x * ROWS;

  for (int i = tid * 4; i < 128 * DOUT; i += 256 * 4)
    *(float4*)(wlds + i) = *(const float4*)(W + i);
  for (int i = tid * 4; i < ROWS * 128; i += 256 * 4) {
    const int r = i >> 7, k = i & 127;
    const int row = rowbase + r;
    float4 v = make_float4(0.f, 0.f, 0.f, 0.f);
    if (row < N) v = *(const float4*)(x + (size_t)row * 128 + k);
    *(float4*)(xlds + i) = v;
  }
  __syncthreads();

  const int c0 = tid & 31;
  const int rg = tid >> 5;  // 0..7
  float acc[RT][CT];
#pragma unroll
  for (int r = 0; r < RT; ++r)
#pragma unroll
    for (int cc = 0; cc < CT; ++cc) acc[r][cc] = 0.f;

  for (int k = 0; k < 128; k += 4) {
    float4 xv[RT];
#pragma unroll
    for (int r = 0; r < RT; ++r)
      xv[r] = *(const float4*)(xlds + (rg * RT + r) * 128 + k);
#pragma unroll
    for (int kk = 0; kk < 4; ++kk) {
      float wv[CT];
#pragma unroll
      for (int cc = 0; cc < CT; ++cc)
        wv[cc] = wlds[(k + kk) * DOUT + c0 + 32 * cc];
#pragma unroll
      for (int r = 0; r < RT; ++r) {
        const float xk = (kk == 0) ? xv[r].x : (kk == 1) ? xv[r].y
                        : (kk == 2) ? xv[r].z : xv[r].w;
#pragma unroll
        for (int cc = 0; cc < CT; ++cc)
          acc[r][cc] = fmaf(xk, wv[cc], acc[r][cc]);
      }
    }
  }

#pragma unroll
  for (int r = 0; r < RT; ++r) {
    const int row = rowbase + rg * RT + r;
    if (row >= N) continue;
    const float d = dis[row];
#pragma unroll
    for (int cc = 0; cc < CT; ++cc)
      hs[(size_t)row * DOUT + c0 + 32 * cc] = d * acc[r][cc];
  }
}

// ---------------------------------------------------------------------------
// out[i] = dis[i]*(sum_e w_e*hs[src_e] + hs[i]) + b   (+ relu + dropout)
// one wave per destination node
// ---------------------------------------------------------------------------
template <int DOUT, bool ACT>
__global__ __launch_bounds__(256) void aggregate_k(
    const uint2* __restrict__ srcw, const u32* __restrict__ offsets,
    const float* __restrict__ dis, const float* __restrict__ hs,
    const float* __restrict__ bias, float* __restrict__ out, int N,
    u32 ka, u32 kb) {
  const int lane = threadIdx.x & 63;
  const int wid = blockIdx.x * 4 + (threadIdx.x >> 6);
  if (wid >= N) return;
  const u32 beg = offsets[wid], end = offsets[wid + 1];

  if constexpr (DOUT == 128) {
    const int f0 = lane * 2;
    float ax = 0.f, ay = 0.f;
    u32 e = beg;
    for (; e + 4 <= end; e += 4) {
      const uint2 s0 = srcw[e + 0], s1 = srcw[e + 1], s2 = srcw[e + 2], s3 = srcw[e + 3];
      const float2 v0 = *(const float2*)(hs + (size_t)s0.x * 128 + f0);
      const float2 v1 = *(const float2*)(hs + (size_t)s1.x * 128 + f0);
      const float2 v2 = *(const float2*)(hs + (size_t)s2.x * 128 + f0);
      const float2 v3 = *(const float2*)(hs + (size_t)s3.x * 128 + f0);
      const float w0 = __uint_as_float(s0.y), w1 = __uint_as_float(s1.y);
      const float w2 = __uint_as_float(s2.y), w3 = __uint_as_float(s3.y);
      ax = fmaf(w0, v0.x, ax); ay = fmaf(w0, v0.y, ay);
      ax = fmaf(w1, v1.x, ax); ay = fmaf(w1, v1.y, ay);
      ax = fmaf(w2, v2.x, ax); ay = fmaf(w2, v2.y, ay);
      ax = fmaf(w3, v3.x, ax); ay = fmaf(w3, v3.y, ay);
    }
    for (; e < end; ++e) {
      const uint2 s0 = srcw[e];
      const float2 v0 = *(const float2*)(hs + (size_t)s0.x * 128 + f0);
      const float w0 = __uint_as_float(s0.y);
      ax = fmaf(w0, v0.x, ax); ay = fmaf(w0, v0.y, ay);
    }
    const float d = dis[wid];
    const float2 sv = *(const float2*)(hs + (size_t)wid * 128 + f0);
    float ox = d * (ax + sv.x) + bias[f0];
    float oy = d * (ay + sv.y) + bias[f0 + 1];
    if constexpr (ACT) {
      ox = fmaxf(ox, 0.f);
      oy = fmaxf(oy, 0.f);
      const u32 idx = (u32)wid * 128u + (u32)f0;
      ox = keep_elem(ka, kb, idx) ? 2.f * ox : 0.f;
      oy = keep_elem(ka, kb, idx + 1u) ? 2.f * oy : 0.f;
    }
    *(float2*)(out + (size_t)wid * 128 + f0) = make_float2(ox, oy);
  } else {
    float a = 0.f;
    u32 e = beg;
    for (; e + 4 <= end; e += 4) {
      const uint2 s0 = srcw[e + 0], s1 = srcw[e + 1], s2 = srcw[e + 2], s3 = srcw[e + 3];
      const float v0 = hs[(size_t)s0.x * 64 + lane];
      const float v1 = hs[(size_t)s1.x * 64 + lane];
      const float v2 = hs[(size_t)s2.x * 64 + lane];
      const float v3 = hs[(size_t)s3.x * 64 + lane];
      a = fmaf(__uint_as_float(s0.y), v0, a);
      a = fmaf(__uint_as_float(s1.y), v1, a);
      a = fmaf(__uint_as_float(s2.y), v2, a);
      a = fmaf(__uint_as_float(s3.y), v3, a);
    }
    for (; e < end; ++e) {
      const uint2 s0 = srcw[e];
      a = fmaf(__uint_as_float(s0.y), hs[(size_t)s0.x * 64 + lane], a);
    }
    const float d = dis[wid];
    const float o = d * (a + hs[(size_t)wid * 64 + lane]) + bias[lane];
    out[(size_t)wid * 64 + lane] = o;
  }
}

// ---------------------------------------------------------------------------
extern "C" void kernel_launch(void* const* d_in, const int* in_sizes, int n_in,
                              void* d_out, int out_size, void* d_ws, size_t ws_size,
                              hipStream_t stream) {
  const float* x0 = (const float*)d_in[0];
  const u32* ei   = (const u32*)d_in[1];
  const float* ew = (const float*)d_in[2];
  const float* W1 = (const float*)d_in[3];
  const float* b1 = (const float*)d_in[4];
  const float* W2 = (const float*)d_in[5];
  const float* b2 = (const float*)d_in[6];
  const float* W3 = (const float*)d_in[7];
  const float* b3 = (const float*)d_in[8];

  const int N = in_sizes[0] / 128;
  const int E = in_sizes[2];

  char* p = (char*)d_ws;
  auto carve = [&](size_t bytes) -> char* {
    char* q = p;
    p += (bytes + 255) & ~(size_t)255;
    return q;
  };
  float* deg    = (float*)carve((size_t)N * 4);
  u32*   counts = (u32*)carve((size_t)N * 4);
  u32*   offs   = (u32*)carve((size_t)(N + 1) * 4);
  u32*   cursor = (u32*)carve((size_t)N * 4);
  float* dis    = (float*)carve((size_t)N * 4);
  u32*   flag   = (u32*)carve(256);
  uint2* srcw   = (uint2*)carve((size_t)E * 8);
  float* hs     = (float*)carve((size_t)N * 128 * 4);
  float* xbuf   = (float*)carve((size_t)N * 128 * 4);

  const int egrid = (E + 255) / 256;
  const int ngrid = (N + 255) / 256;
  const int ggrid = (N + 63) / 64;
  const int agrid = (N + 3) / 4;

  detect_kernel<<<1, 64, 0, stream>>>(ei, flag);
  zero2<<<ngrid, 256, 0, stream>>>(deg, counts, N);
  edge_deg_count<<<egrid, 256, 0, stream>>>(ei, ew, deg, counts, E, flag);
  scan_kernel<<<1, 1024, 0, stream>>>(counts, offs, cursor, deg, dis, N);
  scatter_kernel<<<egrid, 256, 0, stream>>>(ei, ew, cursor, srcw, E, flag);

  // layer 1
  gemm_scale<128><<<ggrid, 256, 0, stream>>>(x0, W1, dis, hs, N);
  aggregate_k<128, true><<<agrid, 256, 0, stream>>>(srcw, offs, dis, hs, b1, xbuf, N, DK1.a, DK1.b);
  // layer 2
  gemm_scale<128><<<ggrid, 256, 0, stream>>>(xbuf, W2, dis, hs, N);
  aggregate_k<128, true><<<agrid, 256, 0, stream>>>(srcw, offs, dis, hs, b2, xbuf, N, DK2.a, DK2.b);
  // layer 3
  gemm_scale<64><<<ggrid, 256, 0, stream>>>(xbuf, W3, dis, hs, N);
  aggregate_k<64, false><<<agrid, 256, 0, stream>>>(srcw, offs, dis, hs, b3, (float*)d_out, N, 0u, 0u);
}

// Round 4
// 1364.150 us; speedup vs baseline: 1.1806x; 1.1806x over previous
//
#include <hip/hip_runtime.h>
#include <hip/hip_bf16.h>
#include <stdint.h>

typedef unsigned int u32;

// ---------------------------------------------------------------------------
// threefry2x32 (matches jax/_src/prng.py threefry2x32 exactly)
// ---------------------------------------------------------------------------
__host__ __device__ constexpr void tf_block(u32 k0, u32 k1, u32& x0, u32& x1) {
  const u32 ks2 = k0 ^ k1 ^ 0x1BD11BDAu;
  const u32 ks[3] = {k0, k1, ks2};
  const int R[2][4] = {{13, 15, 26, 6}, {17, 29, 16, 24}};
  x0 += k0;
  x1 += k1;
  for (int i = 0; i < 5; ++i) {
    for (int j = 0; j < 4; ++j) {
      const int r = R[i & 1][j];
      x0 += x1;
      x1 = (x1 << r) | (x1 >> (32 - r));
      x1 ^= x0;
    }
    x0 += ks[(i + 1) % 3];
    x1 += ks[(i + 2) % 3] + (u32)(i + 1);
  }
}

struct KeyPair { u32 a, b; };
__host__ __device__ constexpr KeyPair tf_pair(u32 k0, u32 k1, u32 c0, u32 c1) {
  u32 x0 = c0, x1 = c1;
  tf_block(k0, k1, x0, x1);
  return KeyPair{x0, x1};
}

// jax.random.key(42) -> (0,42). partitionable split: dk_i = threefry(key,(0,i))
constexpr KeyPair DK1 = tf_pair(0u, 42u, 0u, 0u);
constexpr KeyPair DK2 = tf_pair(0u, 42u, 0u, 1u);

// partitionable random_bits(32): bits = y0 ^ y1 of threefry(dk, (0, flat_idx));
// uniform<0.5  <=>  MSB(bits)==0
__device__ __forceinline__ bool keep_elem(u32 ka, u32 kb, u32 idx) {
  u32 x0 = 0u, x1 = idx;
  tf_block(ka, kb, x0, x1);
  return ((x0 ^ x1) & 0x80000000u) == 0u;
}

// ---------------------------------------------------------------------------
// edge_index dtype detection: int64 => all odd u32 words (hi) are zero
// ---------------------------------------------------------------------------
__global__ void detect_kernel(const u32* __restrict__ ei, u32* __restrict__ flag) {
  if (threadIdx.x == 0) {
    u32 acc = 0;
    for (int k = 0; k < 32; ++k) acc |= ei[2 * k + 1];
    *flag = (acc == 0u) ? 1u : 0u;
  }
}

__global__ void zero_counts(u32* __restrict__ b, int n) {
  const int i = blockIdx.x * blockDim.x + threadIdx.x;
  if (i < n) b[i] = 0u;
}

// histogram: in-degree counts only (1 atomic per edge; weighted degree is
// computed AFTER the sort with zero atomics in degsum_kernel)
__global__ __launch_bounds__(256) void edge_count(
    const u32* __restrict__ ei, u32* __restrict__ counts, int E,
    const u32* __restrict__ flag) {
  const int e = blockIdx.x * 256 + threadIdx.x;
  if (e >= E) return;
  const bool is64 = (*flag != 0u);
  const u32 c = is64 ? ei[2 * ((size_t)E + e)] : ei[(size_t)E + e];
  atomicAdd(&counts[c], 1u);
}

// single-block exclusive scan of counts -> offsets (+cursor copy)
__global__ __launch_bounds__(1024) void scan_kernel(
    const u32* __restrict__ counts, u32* __restrict__ offsets,
    u32* __restrict__ cursor, int N) {
  __shared__ u32 wsum[16];
  __shared__ u32 carry_s;
  const int t = threadIdx.x, lane = t & 63, wv = t >> 6;
  if (t == 0) carry_s = 0u;
  __syncthreads();
  for (int base = 0; base < N; base += 1024) {
    const int i = base + t;
    const u32 v = (i < N) ? counts[i] : 0u;
    u32 inc = v;
#pragma unroll
    for (int off = 1; off < 64; off <<= 1) {
      const u32 tmp = (u32)__shfl_up((int)inc, off, 64);
      if (lane >= off) inc += tmp;
    }
    if (lane == 63) wsum[wv] = inc;
    __syncthreads();
    if (wv == 0) {
      u32 wval = (lane < 16) ? wsum[lane] : 0u;
#pragma unroll
      for (int off = 1; off < 16; off <<= 1) {
        const u32 tmp = (u32)__shfl_up((int)wval, off, 64);
        if (lane >= off) wval += tmp;
      }
      if (lane < 16) wsum[lane] = wval;  // inclusive wave sums
    }
    __syncthreads();
    const u32 c0 = carry_s;
    const u32 wpre = (wv == 0) ? 0u : wsum[wv - 1];
    const u32 excl = c0 + wpre + inc - v;
    if (i < N) { offsets[i] = excl; cursor[i] = excl; }
    __syncthreads();
    if (t == 0) carry_s = c0 + wsum[15];
    __syncthreads();
  }
  if (t == 0) offsets[N] = carry_s;
}

// counting-sort scatter: group (src, w) by destination
__global__ __launch_bounds__(256) void scatter_kernel(
    const u32* __restrict__ ei, const float* __restrict__ ew,
    u32* __restrict__ cursor, uint2* __restrict__ srcw, int E,
    const u32* __restrict__ flag) {
  const int e = blockIdx.x * 256 + threadIdx.x;
  if (e >= E) return;
  const bool is64 = (*flag != 0u);
  u32 r, c;
  if (is64) { r = ei[2 * (size_t)e]; c = ei[2 * ((size_t)E + e)]; }
  else      { r = ei[e];             c = ei[(size_t)E + e]; }
  const u32 pos = atomicAdd(&cursor[c], 1u);
  srcw[pos] = make_uint2(r, __float_as_uint(ew[e]));
}

// atomic-free weighted degree from the sorted edge list: one wave per node
// sums its contiguous CSR segment, then dis = rsqrt(deg + 1)  (self-loop w=1)
__global__ __launch_bounds__(256) void degsum_kernel(
    const uint2* __restrict__ srcw, const u32* __restrict__ offsets,
    float* __restrict__ dis, int N) {
  const int lane = threadIdx.x & 63;
  const int wid = blockIdx.x * 4 + (threadIdx.x >> 6);
  if (wid >= N) return;
  const u32 beg = offsets[wid], end = offsets[wid + 1];
  float a = 0.f;
  for (u32 e = beg + lane; e < end; e += 64)
    a += __uint_as_float(srcw[e].y);
#pragma unroll
  for (int off = 32; off > 0; off >>= 1)
    a += __shfl_xor(a, off, 64);
  if (lane == 0) dis[wid] = rsqrtf(a + 1.0f);
}

// ---------------------------------------------------------------------------
// hs = dis .* (x @ W)   fp32, W + x tile in LDS
// ---------------------------------------------------------------------------
template <int DOUT>
__global__ __launch_bounds__(256) void gemm_scale(
    const float* __restrict__ x, const float* __restrict__ W,
    const float* __restrict__ dis, float* __restrict__ hs, int N) {
  static_assert(DOUT == 128 || DOUT == 64, "");
  constexpr int ROWS = 64;
  constexpr int CT = DOUT / 32;  // cols per thread
  constexpr int RT = 8;          // rows per thread
  __shared__ float wlds[128 * DOUT];
  __shared__ float xlds[ROWS * 128];

  const int tid = threadIdx.x;
  const int rowbase = blockIdx.x * ROWS;

  for (int i = tid * 4; i < 128 * DOUT; i += 256 * 4)
    *(float4*)(wlds + i) = *(const float4*)(W + i);
  for (int i = tid * 4; i < ROWS * 128; i += 256 * 4) {
    const int r = i >> 7, k = i & 127;
    const int row = rowbase + r;
    float4 v = make_float4(0.f, 0.f, 0.f, 0.f);
    if (row < N) v = *(const float4*)(x + (size_t)row * 128 + k);
    *(float4*)(xlds + i) = v;
  }
  __syncthreads();

  const int c0 = tid & 31;
  const int rg = tid >> 5;  // 0..7
  float acc[RT][CT];
#pragma unroll
  for (int r = 0; r < RT; ++r)
#pragma unroll
    for (int cc = 0; cc < CT; ++cc) acc[r][cc] = 0.f;

  for (int k = 0; k < 128; k += 4) {
    float4 xv[RT];
#pragma unroll
    for (int r = 0; r < RT; ++r)
      xv[r] = *(const float4*)(xlds + (rg * RT + r) * 128 + k);
#pragma unroll
    for (int kk = 0; kk < 4; ++kk) {
      float wv[CT];
#pragma unroll
      for (int cc = 0; cc < CT; ++cc)
        wv[cc] = wlds[(k + kk) * DOUT + c0 + 32 * cc];
#pragma unroll
      for (int r = 0; r < RT; ++r) {
        const float xk = (kk == 0) ? xv[r].x : (kk == 1) ? xv[r].y
                        : (kk == 2) ? xv[r].z : xv[r].w;
#pragma unroll
        for (int cc = 0; cc < CT; ++cc)
          acc[r][cc] = fmaf(xk, wv[cc], acc[r][cc]);
      }
    }
  }

#pragma unroll
  for (int r = 0; r < RT; ++r) {
    const int row = rowbase + rg * RT + r;
    if (row >= N) continue;
    const float d = dis[row];
#pragma unroll
    for (int cc = 0; cc < CT; ++cc)
      hs[(size_t)row * DOUT + c0 + 32 * cc] = d * acc[r][cc];
  }
}

// ---------------------------------------------------------------------------
// out[i] = dis[i]*(sum_e w_e*hs[src_e] + hs[i]) + b   (+ relu + dropout)
// one wave per destination node
// ---------------------------------------------------------------------------
template <int DOUT, bool ACT>
__global__ __launch_bounds__(256) void aggregate_k(
    const uint2* __restrict__ srcw, const u32* __restrict__ offsets,
    const float* __restrict__ dis, const float* __restrict__ hs,
    const float* __restrict__ bias, float* __restrict__ out, int N,
    u32 ka, u32 kb) {
  const int lane = threadIdx.x & 63;
  const int wid = blockIdx.x * 4 + (threadIdx.x >> 6);
  if (wid >= N) return;
  const u32 beg = offsets[wid], end = offsets[wid + 1];

  if constexpr (DOUT == 128) {
    const int f0 = lane * 2;
    float ax = 0.f, ay = 0.f;
    u32 e = beg;
    for (; e + 4 <= end; e += 4) {
      const uint2 s0 = srcw[e + 0], s1 = srcw[e + 1], s2 = srcw[e + 2], s3 = srcw[e + 3];
      const float2 v0 = *(const float2*)(hs + (size_t)s0.x * 128 + f0);
      const float2 v1 = *(const float2*)(hs + (size_t)s1.x * 128 + f0);
      const float2 v2 = *(const float2*)(hs + (size_t)s2.x * 128 + f0);
      const float2 v3 = *(const float2*)(hs + (size_t)s3.x * 128 + f0);
      const float w0 = __uint_as_float(s0.y), w1 = __uint_as_float(s1.y);
      const float w2 = __uint_as_float(s2.y), w3 = __uint_as_float(s3.y);
      ax = fmaf(w0, v0.x, ax); ay = fmaf(w0, v0.y, ay);
      ax = fmaf(w1, v1.x, ax); ay = fmaf(w1, v1.y, ay);
      ax = fmaf(w2, v2.x, ax); ay = fmaf(w2, v2.y, ay);
      ax = fmaf(w3, v3.x, ax); ay = fmaf(w3, v3.y, ay);
    }
    for (; e < end; ++e) {
      const uint2 s0 = srcw[e];
      const float2 v0 = *(const float2*)(hs + (size_t)s0.x * 128 + f0);
      const float w0 = __uint_as_float(s0.y);
      ax = fmaf(w0, v0.x, ax); ay = fmaf(w0, v0.y, ay);
    }
    const float d = dis[wid];
    const float2 sv = *(const float2*)(hs + (size_t)wid * 128 + f0);
    float ox = d * (ax + sv.x) + bias[f0];
    float oy = d * (ay + sv.y) + bias[f0 + 1];
    if constexpr (ACT) {
      ox = fmaxf(ox, 0.f);
      oy = fmaxf(oy, 0.f);
      const u32 idx = (u32)wid * 128u + (u32)f0;
      ox = keep_elem(ka, kb, idx) ? 2.f * ox : 0.f;
      oy = keep_elem(ka, kb, idx + 1u) ? 2.f * oy : 0.f;
    }
    *(float2*)(out + (size_t)wid * 128 + f0) = make_float2(ox, oy);
  } else {
    float a = 0.f;
    u32 e = beg;
    for (; e + 4 <= end; e += 4) {
      const uint2 s0 = srcw[e + 0], s1 = srcw[e + 1], s2 = srcw[e + 2], s3 = srcw[e + 3];
      const float v0 = hs[(size_t)s0.x * 64 + lane];
      const float v1 = hs[(size_t)s1.x * 64 + lane];
      const float v2 = hs[(size_t)s2.x * 64 + lane];
      const float v3 = hs[(size_t)s3.x * 64 + lane];
      a = fmaf(__uint_as_float(s0.y), v0, a);
      a = fmaf(__uint_as_float(s1.y), v1, a);
      a = fmaf(__uint_as_float(s2.y), v2, a);
      a = fmaf(__uint_as_float(s3.y), v3, a);
    }
    for (; e < end; ++e) {
      const uint2 s0 = srcw[e];
      a = fmaf(__uint_as_float(s0.y), hs[(size_t)s0.x * 64 + lane], a);
    }
    const float d = dis[wid];
    const float o = d * (a + hs[(size_t)wid * 64 + lane]) + bias[lane];
    out[(size_t)wid * 64 + lane] = o;
  }
}

// ---------------------------------------------------------------------------
extern "C" void kernel_launch(void* const* d_in, const int* in_sizes, int n_in,
                              void* d_out, int out_size, void* d_ws, size_t ws_size,
                              hipStream_t stream) {
  const float* x0 = (const float*)d_in[0];
  const u32* ei   = (const u32*)d_in[1];
  const float* ew = (const float*)d_in[2];
  const float* W1 = (const float*)d_in[3];
  const float* b1 = (const float*)d_in[4];
  const float* W2 = (const float*)d_in[5];
  const float* b2 = (const float*)d_in[6];
  const float* W3 = (const float*)d_in[7];
  const float* b3 = (const float*)d_in[8];

  const int N = in_sizes[0] / 128;
  const int E = in_sizes[2];

  char* p = (char*)d_ws;
  auto carve = [&](size_t bytes) -> char* {
    char* q = p;
    p += (bytes + 255) & ~(size_t)255;
    return q;
  };
  u32*   counts = (u32*)carve((size_t)N * 4);
  u32*   offs   = (u32*)carve((size_t)(N + 1) * 4);
  u32*   cursor = (u32*)carve((size_t)N * 4);
  float* dis    = (float*)carve((size_t)N * 4);
  u32*   flag   = (u32*)carve(256);
  uint2* srcw   = (uint2*)carve((size_t)E * 8);
  float* hs     = (float*)carve((size_t)N * 128 * 4);
  float* xbuf   = (float*)carve((size_t)N * 128 * 4);

  const int egrid = (E + 255) / 256;
  const int ngrid = (N + 255) / 256;
  const int ggrid = (N + 63) / 64;
  const int agrid = (N + 3) / 4;

  detect_kernel<<<1, 64, 0, stream>>>(ei, flag);
  zero_counts<<<ngrid, 256, 0, stream>>>(counts, N);
  edge_count<<<egrid, 256, 0, stream>>>(ei, counts, E, flag);
  scan_kernel<<<1, 1024, 0, stream>>>(counts, offs, cursor, N);
  scatter_kernel<<<egrid, 256, 0, stream>>>(ei, ew, cursor, srcw, E, flag);
  degsum_kernel<<<agrid, 256, 0, stream>>>(srcw, offs, dis, N);

  // layer 1
  gemm_scale<128><<<ggrid, 256, 0, stream>>>(x0, W1, dis, hs, N);
  aggregate_k<128, true><<<agrid, 256, 0, stream>>>(srcw, offs, dis, hs, b1, xbuf, N, DK1.a, DK1.b);
  // layer 2
  gemm_scale<128><<<ggrid, 256, 0, stream>>>(xbuf, W2, dis, hs, N);
  aggregate_k<128, true><<<agrid, 256, 0, stream>>>(srcw, offs, dis, hs, b2, xbuf, N, DK2.a, DK2.b);
  // layer 3
  gemm_scale<64><<<ggrid, 256, 0, stream>>>(xbuf, W3, dis, hs, N);
  aggregate_k<64, false><<<agrid, 256, 0, stream>>>(srcw, offs, dis, hs, b3, (float*)d_out, N, 0u, 0u);
}

// Round 7
// 1174.381 us; speedup vs baseline: 1.3713x; 1.1616x over previous
//
#include <hip/hip_runtime.h>
#include <hip/hip_bf16.h>
#include <hip/hip_fp16.h>
#include <stdint.h>

typedef unsigned int u32;

// ---------------------------------------------------------------------------
// threefry2x32 (matches jax/_src/prng.py threefry2x32 exactly)
// ---------------------------------------------------------------------------
__host__ __device__ constexpr void tf_block(u32 k0, u32 k1, u32& x0, u32& x1) {
  const u32 ks2 = k0 ^ k1 ^ 0x1BD11BDAu;
  const u32 ks[3] = {k0, k1, ks2};
  const int R[2][4] = {{13, 15, 26, 6}, {17, 29, 16, 24}};
  x0 += k0;
  x1 += k1;
  for (int i = 0; i < 5; ++i) {
    for (int j = 0; j < 4; ++j) {
      const int r = R[i & 1][j];
      x0 += x1;
      x1 = (x1 << r) | (x1 >> (32 - r));
      x1 ^= x0;
    }
    x0 += ks[(i + 1) % 3];
    x1 += ks[(i + 2) % 3] + (u32)(i + 1);
  }
}

struct KeyPair { u32 a, b; };
__host__ __device__ constexpr KeyPair tf_pair(u32 k0, u32 k1, u32 c0, u32 c1) {
  u32 x0 = c0, x1 = c1;
  tf_block(k0, k1, x0, x1);
  return KeyPair{x0, x1};
}

// jax.random.key(42) -> (0,42). partitionable split: dk_i = threefry(key,(0,i))
constexpr KeyPair DK1 = tf_pair(0u, 42u, 0u, 0u);
constexpr KeyPair DK2 = tf_pair(0u, 42u, 0u, 1u);

// partitionable random_bits(32): bits = y0 ^ y1 of threefry(dk, (0, flat_idx));
// uniform<0.5  <=>  MSB(bits)==0
__device__ __forceinline__ bool keep_elem(u32 ka, u32 kb, u32 idx) {
  u32 x0 = 0u, x1 = idx;
  tf_block(ka, kb, x0, x1);
  return ((x0 ^ x1) & 0x80000000u) == 0u;
}

// ---------------------------------------------------------------------------
// edge_index dtype detection: int64 => all odd u32 words (hi) are zero
// ---------------------------------------------------------------------------
__global__ void detect_kernel(const u32* __restrict__ ei, u32* __restrict__ flag) {
  if (threadIdx.x == 0) {
    u32 acc = 0;
    for (int k = 0; k < 32; ++k) acc |= ei[2 * k + 1];
    *flag = (acc == 0u) ? 1u : 0u;
  }
}

__global__ void zero_counts(u32* __restrict__ b, int n) {
  const int i = blockIdx.x * blockDim.x + threadIdx.x;
  if (i < n) b[i] = 0u;
}

// histogram: in-degree counts only (1 atomic per edge; weighted degree is
// computed AFTER the sort with zero atomics in degsum_kernel)
__global__ __launch_bounds__(256) void edge_count(
    const u32* __restrict__ ei, u32* __restrict__ counts, int E,
    const u32* __restrict__ flag) {
  const int e = blockIdx.x * 256 + threadIdx.x;
  if (e >= E) return;
  const bool is64 = (*flag != 0u);
  const u32 c = is64 ? ei[2 * ((size_t)E + e)] : ei[(size_t)E + e];
  atomicAdd(&counts[c], 1u);
}

// single-block exclusive scan of counts -> offsets (+cursor copy)
__global__ __launch_bounds__(1024) void scan_kernel(
    const u32* __restrict__ counts, u32* __restrict__ offsets,
    u32* __restrict__ cursor, int N) {
  __shared__ u32 wsum[16];
  __shared__ u32 carry_s;
  const int t = threadIdx.x, lane = t & 63, wv = t >> 6;
  if (t == 0) carry_s = 0u;
  __syncthreads();
  for (int base = 0; base < N; base += 1024) {
    const int i = base + t;
    const u32 v = (i < N) ? counts[i] : 0u;
    u32 inc = v;
#pragma unroll
    for (int off = 1; off < 64; off <<= 1) {
      const u32 tmp = (u32)__shfl_up((int)inc, off, 64);
      if (lane >= off) inc += tmp;
    }
    if (lane == 63) wsum[wv] = inc;
    __syncthreads();
    if (wv == 0) {
      u32 wval = (lane < 16) ? wsum[lane] : 0u;
#pragma unroll
      for (int off = 1; off < 16; off <<= 1) {
        const u32 tmp = (u32)__shfl_up((int)wval, off, 64);
        if (lane >= off) wval += tmp;
      }
      if (lane < 16) wsum[lane] = wval;  // inclusive wave sums
    }
    __syncthreads();
    const u32 c0 = carry_s;
    const u32 wpre = (wv == 0) ? 0u : wsum[wv - 1];
    const u32 excl = c0 + wpre + inc - v;
    if (i < N) { offsets[i] = excl; cursor[i] = excl; }
    __syncthreads();
    if (t == 0) carry_s = c0 + wsum[15];
    __syncthreads();
  }
  if (t == 0) offsets[N] = carry_s;
}

// counting-sort scatter: group (src, w) by destination
__global__ __launch_bounds__(256) void scatter_kernel(
    const u32* __restrict__ ei, const float* __restrict__ ew,
    u32* __restrict__ cursor, uint2* __restrict__ srcw, int E,
    const u32* __restrict__ flag) {
  const int e = blockIdx.x * 256 + threadIdx.x;
  if (e >= E) return;
  const bool is64 = (*flag != 0u);
  u32 r, c;
  if (is64) { r = ei[2 * (size_t)e]; c = ei[2 * ((size_t)E + e)]; }
  else      { r = ei[e];             c = ei[(size_t)E + e]; }
  const u32 pos = atomicAdd(&cursor[c], 1u);
  srcw[pos] = make_uint2(r, __float_as_uint(ew[e]));
}

// atomic-free weighted degree from the sorted edge list: one wave per node
// sums its contiguous CSR segment, then dis = rsqrt(deg + 1)  (self-loop w=1)
__global__ __launch_bounds__(256) void degsum_kernel(
    const uint2* __restrict__ srcw, const u32* __restrict__ offsets,
    float* __restrict__ dis, int N) {
  const int lane = threadIdx.x & 63;
  const int wid = blockIdx.x * 4 + (threadIdx.x >> 6);
  if (wid >= N) return;
  const u32 beg = offsets[wid], end = offsets[wid + 1];
  float a = 0.f;
  for (u32 e = beg + lane; e < end; e += 64)
    a += __uint_as_float(srcw[e].y);
#pragma unroll
  for (int off = 32; off > 0; off >>= 1)
    a += __shfl_xor(a, off, 64);
  if (lane == 0) dis[wid] = rsqrtf(a + 1.0f);
}

// ---------------------------------------------------------------------------
// hs = fp16( dis .* (x @ W) )   fp32 math, W + x tile in LDS, fp16 store
// (fp16 not bf16: 2^-11 rounding keeps final absmax ~1e-4 vs 9.3e-4 thresh)
// ---------------------------------------------------------------------------
template <int DOUT>
__global__ __launch_bounds__(256) void gemm_scale(
    const float* __restrict__ x, const float* __restrict__ W,
    const float* __restrict__ dis, __half* __restrict__ hs, int N) {
  static_assert(DOUT == 128 || DOUT == 64, "");
  constexpr int ROWS = 64;
  constexpr int CT = DOUT / 32;  // cols per thread
  constexpr int RT = 8;          // rows per thread
  __shared__ float wlds[128 * DOUT];
  __shared__ float xlds[ROWS * 128];

  const int tid = threadIdx.x;
  const int rowbase = blockIdx.x * ROWS;

  for (int i = tid * 4; i < 128 * DOUT; i += 256 * 4)
    *(float4*)(wlds + i) = *(const float4*)(W + i);
  for (int i = tid * 4; i < ROWS * 128; i += 256 * 4) {
    const int r = i >> 7, k = i & 127;
    const int row = rowbase + r;
    float4 v = make_float4(0.f, 0.f, 0.f, 0.f);
    if (row < N) v = *(const float4*)(x + (size_t)row * 128 + k);
    *(float4*)(xlds + i) = v;
  }
  __syncthreads();

  const int c0 = tid & 31;
  const int rg = tid >> 5;  // 0..7
  float acc[RT][CT];
#pragma unroll
  for (int r = 0; r < RT; ++r)
#pragma unroll
    for (int cc = 0; cc < CT; ++cc) acc[r][cc] = 0.f;

  for (int k = 0; k < 128; k += 4) {
    float4 xv[RT];
#pragma unroll
    for (int r = 0; r < RT; ++r)
      xv[r] = *(const float4*)(xlds + (rg * RT + r) * 128 + k);
#pragma unroll
    for (int kk = 0; kk < 4; ++kk) {
      float wv[CT];
#pragma unroll
      for (int cc = 0; cc < CT; ++cc)
        wv[cc] = wlds[(k + kk) * DOUT + c0 + 32 * cc];
#pragma unroll
      for (int r = 0; r < RT; ++r) {
        const float xk = (kk == 0) ? xv[r].x : (kk == 1) ? xv[r].y
                        : (kk == 2) ? xv[r].z : xv[r].w;
#pragma unroll
        for (int cc = 0; cc < CT; ++cc)
          acc[r][cc] = fmaf(xk, wv[cc], acc[r][cc]);
      }
    }
  }

#pragma unroll
  for (int r = 0; r < RT; ++r) {
    const int row = rowbase + rg * RT + r;
    if (row >= N) continue;
    const float d = dis[row];
#pragma unroll
    for (int cc = 0; cc < CT; ++cc)
      hs[(size_t)row * DOUT + c0 + 32 * cc] = __float2half(d * acc[r][cc]);
  }
}

// ---------------------------------------------------------------------------
// out[i] = dis[i]*(sum_e w_e*hs[src_e] + hs[i]) + b   (+ relu + dropout)
// one wave per destination node; hs rows are fp16 (256B / 128B per row)
// ---------------------------------------------------------------------------
template <int DOUT, bool ACT>
__global__ __launch_bounds__(256) void aggregate_k(
    const uint2* __restrict__ srcw, const u32* __restrict__ offsets,
    const float* __restrict__ dis, const __half* __restrict__ hs,
    const float* __restrict__ bias, float* __restrict__ out, int N,
    u32 ka, u32 kb) {
  const int lane = threadIdx.x & 63;
  const int wid = blockIdx.x * 4 + (threadIdx.x >> 6);
  if (wid >= N) return;
  const u32 beg = offsets[wid], end = offsets[wid + 1];

  if constexpr (DOUT == 128) {
    const int f0 = lane * 2;
    float ax = 0.f, ay = 0.f;
    u32 e = beg;
    for (; e + 4 <= end; e += 4) {
      const uint2 s0 = srcw[e + 0], s1 = srcw[e + 1], s2 = srcw[e + 2], s3 = srcw[e + 3];
      const __half2 h0 = *(const __half2*)(hs + (size_t)s0.x * 128 + f0);
      const __half2 h1 = *(const __half2*)(hs + (size_t)s1.x * 128 + f0);
      const __half2 h2 = *(const __half2*)(hs + (size_t)s2.x * 128 + f0);
      const __half2 h3 = *(const __half2*)(hs + (size_t)s3.x * 128 + f0);
      const float2 v0 = __half22float2(h0);
      const float2 v1 = __half22float2(h1);
      const float2 v2 = __half22float2(h2);
      const float2 v3 = __half22float2(h3);
      const float w0 = __uint_as_float(s0.y), w1 = __uint_as_float(s1.y);
      const float w2 = __uint_as_float(s2.y), w3 = __uint_as_float(s3.y);
      ax = fmaf(w0, v0.x, ax); ay = fmaf(w0, v0.y, ay);
      ax = fmaf(w1, v1.x, ax); ay = fmaf(w1, v1.y, ay);
      ax = fmaf(w2, v2.x, ax); ay = fmaf(w2, v2.y, ay);
      ax = fmaf(w3, v3.x, ax); ay = fmaf(w3, v3.y, ay);
    }
    for (; e < end; ++e) {
      const uint2 s0 = srcw[e];
      const float2 v0 = __half22float2(*(const __half2*)(hs + (size_t)s0.x * 128 + f0));
      const float w0 = __uint_as_float(s0.y);
      ax = fmaf(w0, v0.x, ax); ay = fmaf(w0, v0.y, ay);
    }
    const float d = dis[wid];
    const float2 sv = __half22float2(*(const __half2*)(hs + (size_t)wid * 128 + f0));
    float ox = d * (ax + sv.x) + bias[f0];
    float oy = d * (ay + sv.y) + bias[f0 + 1];
    if constexpr (ACT) {
      ox = fmaxf(ox, 0.f);
      oy = fmaxf(oy, 0.f);
      const u32 idx = (u32)wid * 128u + (u32)f0;
      ox = keep_elem(ka, kb, idx) ? 2.f * ox : 0.f;
      oy = keep_elem(ka, kb, idx + 1u) ? 2.f * oy : 0.f;
    }
    *(float2*)(out + (size_t)wid * 128 + f0) = make_float2(ox, oy);
  } else {
    float a = 0.f;
    u32 e = beg;
    for (; e + 4 <= end; e += 4) {
      const uint2 s0 = srcw[e + 0], s1 = srcw[e + 1], s2 = srcw[e + 2], s3 = srcw[e + 3];
      const float v0 = __half2float(hs[(size_t)s0.x * 64 + lane]);
      const float v1 = __half2float(hs[(size_t)s1.x * 64 + lane]);
      const float v2 = __half2float(hs[(size_t)s2.x * 64 + lane]);
      const float v3 = __half2float(hs[(size_t)s3.x * 64 + lane]);
      a = fmaf(__uint_as_float(s0.y), v0, a);
      a = fmaf(__uint_as_float(s1.y), v1, a);
      a = fmaf(__uint_as_float(s2.y), v2, a);
      a = fmaf(__uint_as_float(s3.y), v3, a);
    }
    for (; e < end; ++e) {
      const uint2 s0 = srcw[e];
      a = fmaf(__uint_as_float(s0.y), __half2float(hs[(size_t)s0.x * 64 + lane]), a);
    }
    const float d = dis[wid];
    const float o = d * (a + __half2float(hs[(size_t)wid * 64 + lane])) + bias[lane];
    out[(size_t)wid * 64 + lane] = o;
  }
}

// ---------------------------------------------------------------------------
extern "C" void kernel_launch(void* const* d_in, const int* in_sizes, int n_in,
                              void* d_out, int out_size, void* d_ws, size_t ws_size,
                              hipStream_t stream) {
  const float* x0 = (const float*)d_in[0];
  const u32* ei   = (const u32*)d_in[1];
  const float* ew = (const float*)d_in[2];
  const float* W1 = (const float*)d_in[3];
  const float* b1 = (const float*)d_in[4];
  const float* W2 = (const float*)d_in[5];
  const float* b2 = (const float*)d_in[6];
  const float* W3 = (const float*)d_in[7];
  const float* b3 = (const float*)d_in[8];

  const int N = in_sizes[0] / 128;
  const int E = in_sizes[2];

  char* p = (char*)d_ws;
  auto carve = [&](size_t bytes) -> char* {
    char* q = p;
    p += (bytes + 255) & ~(size_t)255;
    return q;
  };
  u32*    counts = (u32*)carve((size_t)N * 4);
  u32*    offs   = (u32*)carve((size_t)(N + 1) * 4);
  u32*    cursor = (u32*)carve((size_t)N * 4);
  float*  dis    = (float*)carve((size_t)N * 4);
  u32*    flag   = (u32*)carve(256);
  uint2*  srcw   = (uint2*)carve((size_t)E * 8);
  __half* hs     = (__half*)carve((size_t)N * 128 * 2);
  float*  xbuf   = (float*)carve((size_t)N * 128 * 4);

  const int egrid = (E + 255) / 256;
  const int ngrid = (N + 255) / 256;
  const int ggrid = (N + 63) / 64;
  const int agrid = (N + 3) / 4;

  detect_kernel<<<1, 64, 0, stream>>>(ei, flag);
  zero_counts<<<ngrid, 256, 0, stream>>>(counts, N);
  edge_count<<<egrid, 256, 0, stream>>>(ei, counts, E, flag);
  scan_kernel<<<1, 1024, 0, stream>>>(counts, offs, cursor, N);
  scatter_kernel<<<egrid, 256, 0, stream>>>(ei, ew, cursor, srcw, E, flag);
  degsum_kernel<<<agrid, 256, 0, stream>>>(srcw, offs, dis, N);

  // layer 1
  gemm_scale<128><<<ggrid, 256, 0, stream>>>(x0, W1, dis, hs, N);
  aggregate_k<128, true><<<agrid, 256, 0, stream>>>(srcw, offs, dis, hs, b1, xbuf, N, DK1.a, DK1.b);
  // layer 2
  gemm_scale<128><<<ggrid, 256, 0, stream>>>(xbuf, W2, dis, hs, N);
  aggregate_k<128, true><<<agrid, 256, 0, stream>>>(srcw, offs, dis, hs, b2, xbuf, N, DK2.a, DK2.b);
  // layer 3
  gemm_scale<64><<<ggrid, 256, 0, stream>>>(xbuf, W3, dis, hs, N);
  aggregate_k<64, false><<<agrid, 256, 0, stream>>>(srcw, offs, dis, hs, b3, (float*)d_out, N, 0u, 0u);
}

// Round 9
// 1060.190 us; speedup vs baseline: 1.5190x; 1.1077x over previous
//
#include <hip/hip_runtime.h>
#include <hip/hip_bf16.h>
#include <hip/hip_fp16.h>
#include <stdint.h>

typedef unsigned int u32;

constexpr int NB = 128;  // partition blocks (pass A and C must agree)

// ---------------------------------------------------------------------------
// threefry2x32 (matches jax/_src/prng.py threefry2x32 exactly)
// ---------------------------------------------------------------------------
__host__ __device__ constexpr void tf_block(u32 k0, u32 k1, u32& x0, u32& x1) {
  const u32 ks2 = k0 ^ k1 ^ 0x1BD11BDAu;
  const u32 ks[3] = {k0, k1, ks2};
  const int R[2][4] = {{13, 15, 26, 6}, {17, 29, 16, 24}};
  x0 += k0;
  x1 += k1;
  for (int i = 0; i < 5; ++i) {
    for (int j = 0; j < 4; ++j) {
      const int r = R[i & 1][j];
      x0 += x1;
      x1 = (x1 << r) | (x1 >> (32 - r));
      x1 ^= x0;
    }
    x0 += ks[(i + 1) % 3];
    x1 += ks[(i + 2) % 3] + (u32)(i + 1);
  }
}

struct KeyPair { u32 a, b; };
__host__ __device__ constexpr KeyPair tf_pair(u32 k0, u32 k1, u32 c0, u32 c1) {
  u32 x0 = c0, x1 = c1;
  tf_block(k0, k1, x0, x1);
  return KeyPair{x0, x1};
}

// jax.random.key(42) -> (0,42). partitionable split: dk_i = threefry(key,(0,i))
constexpr KeyPair DK1 = tf_pair(0u, 42u, 0u, 0u);
constexpr KeyPair DK2 = tf_pair(0u, 42u, 0u, 1u);

// partitionable random_bits(32): bits = y0 ^ y1 of threefry(dk, (0, flat_idx));
// uniform<0.5  <=>  MSB(bits)==0
__device__ __forceinline__ bool keep_elem(u32 ka, u32 kb, u32 idx) {
  u32 x0 = 0u, x1 = idx;
  tf_block(ka, kb, x0, x1);
  return ((x0 ^ x1) & 0x80000000u) == 0u;
}

// ---------------------------------------------------------------------------
// edge_index dtype detection: int64 => all odd u32 words (hi) are zero
// ---------------------------------------------------------------------------
__global__ void detect_kernel(const u32* __restrict__ ei, u32* __restrict__ flag) {
  if (threadIdx.x == 0) {
    u32 acc = 0;
    for (int k = 0; k < 32; ++k) acc |= ei[2 * k + 1];
    *flag = (acc == 0u) ? 1u : 0u;
  }
}

// ---------------------------------------------------------------------------
// Pass A: per-(bucket,block) exact histogram. bucket = dest >> 7 (128 nodes).
// part_hist[b*NB + blk] = #edges of bucket b in block blk's chunk.
// No zeroing needed: every entry written.
// ---------------------------------------------------------------------------
__global__ __launch_bounds__(256) void partA_count(
    const u32* __restrict__ ei, u32* __restrict__ part_hist,
    int E, int P, int CHUNK, const u32* __restrict__ flag) {
  extern __shared__ u32 lhist[];  // P u32
  const int blk = blockIdx.x;
  for (int i = threadIdx.x; i < P; i += 256) lhist[i] = 0u;
  __syncthreads();
  const bool is64 = (*flag != 0u);
  const int lo = blk * CHUNK;
  const int hi = min(lo + CHUNK, E);
  for (int e = lo + threadIdx.x; e < hi; e += 256) {
    const u32 c = is64 ? ei[2 * ((size_t)E + e)] : ei[(size_t)E + e];
    atomicAdd(&lhist[c >> 7], 1u);
  }
  __syncthreads();
  for (int b = threadIdx.x; b < P; b += 256)
    part_hist[(size_t)b * NB + blk] = lhist[b];
}

// ---------------------------------------------------------------------------
// single-block exclusive scan of part_hist (length L) -> scanned;
// scanned[L] = total. Also writes node_offs[N] = E (CSR terminator).
// ---------------------------------------------------------------------------
__global__ __launch_bounds__(1024) void scan_kernel(
    const u32* __restrict__ in, u32* __restrict__ out, int L,
    u32* __restrict__ node_offs, int N, int E) {
  __shared__ u32 wsum[16];
  __shared__ u32 carry_s;
  const int t = threadIdx.x, lane = t & 63, wv = t >> 6;
  if (t == 0) carry_s = 0u;
  __syncthreads();
  for (int base = 0; base < L; base += 1024) {
    const int i = base + t;
    const u32 v = (i < L) ? in[i] : 0u;
    u32 inc = v;
#pragma unroll
    for (int off = 1; off < 64; off <<= 1) {
      const u32 tmp = (u32)__shfl_up((int)inc, off, 64);
      if (lane >= off) inc += tmp;
    }
    if (lane == 63) wsum[wv] = inc;
    __syncthreads();
    if (wv == 0) {
      u32 wval = (lane < 16) ? wsum[lane] : 0u;
#pragma unroll
      for (int off = 1; off < 16; off <<= 1) {
        const u32 tmp = (u32)__shfl_up((int)wval, off, 64);
        if (lane >= off) wval += tmp;
      }
      if (lane < 16) wsum[lane] = wval;  // inclusive wave sums
    }
    __syncthreads();
    const u32 c0 = carry_s;
    const u32 wpre = (wv == 0) ? 0u : wsum[wv - 1];
    const u32 excl = c0 + wpre + inc - v;
    if (i < L) out[i] = excl;
    __syncthreads();
    if (t == 0) carry_s = c0 + wsum[15];
    __syncthreads();
  }
  if (t == 0) {
    out[L] = carry_s;
    node_offs[N] = (u32)E;
  }
}

// ---------------------------------------------------------------------------
// Pass C: deterministic partition. Each block seeds LDS cursors from its
// exact scanned bases, then writes (src | c_low<<20, w) bucket-grouped.
// Zero global atomics; per-(block,bucket) runs ~32 edges -> coalesced.
// ---------------------------------------------------------------------------
__global__ __launch_bounds__(256) void partC_scatter(
    const u32* __restrict__ ei, const float* __restrict__ ew,
    const u32* __restrict__ scanned, uint2* __restrict__ part,
    int E, int P, int CHUNK, const u32* __restrict__ flag) {
  extern __shared__ u32 lcur[];  // P u32
  const int blk = blockIdx.x;
  for (int b = threadIdx.x; b < P; b += 256)
    lcur[b] = scanned[(size_t)b * NB + blk];
  __syncthreads();
  const bool is64 = (*flag != 0u);
  const int lo = blk * CHUNK;
  const int hi = min(lo + CHUNK, E);
  for (int e = lo + threadIdx.x; e < hi; e += 256) {
    u32 r, c;
    if (is64) { r = ei[2 * (size_t)e]; c = ei[2 * ((size_t)E + e)]; }
    else      { r = ei[e];             c = ei[(size_t)E + e]; }
    const u32 pos = atomicAdd(&lcur[c >> 7], 1u);
    part[pos] = make_uint2(r | ((c & 127u) << 20), __float_as_uint(ew[e]));
  }
}

// ---------------------------------------------------------------------------
// Phase 2: one block per bucket (128 nodes, ~4K edges, L2-resident window).
// Count per node + weighted degree (LDS atomics), serial 128-scan, write
// node_offs + dis (= rsqrt(deg+1), absorbing old degsum_kernel), then
// scatter to final CSR positions in srcw.
// ---------------------------------------------------------------------------
__global__ __launch_bounds__(256) void bucket_sort(
    const uint2* __restrict__ part, const u32* __restrict__ scanned,
    u32* __restrict__ node_offs, float* __restrict__ dis,
    uint2* __restrict__ srcw, int N) {
  __shared__ u32 cnt[128];
  __shared__ float wsum[128];
  __shared__ u32 excl[128];
  const int b = blockIdx.x;
  const int t = threadIdx.x;
  const u32 beg = scanned[(size_t)b * NB];
  const u32 end = scanned[(size_t)(b + 1) * NB];
  if (t < 128) { cnt[t] = 0u; wsum[t] = 0.f; }
  __syncthreads();
  for (u32 e = beg + t; e < end; e += 256) {
    const uint2 it = part[e];
    const u32 nl = it.x >> 20;
    atomicAdd(&cnt[nl], 1u);
    atomicAdd(&wsum[nl], __uint_as_float(it.y));
  }
  __syncthreads();
  if (t == 0) {
    u32 s = 0;
    for (int i = 0; i < 128; ++i) { excl[i] = s; s += cnt[i]; }
  }
  __syncthreads();
  const int node0 = b << 7;
  if (t < 128) {
    const int node = node0 + t;
    if (node < N) {
      node_offs[node] = beg + excl[t];
      dis[node] = rsqrtf(wsum[t] + 1.0f);
    }
    cnt[t] = excl[t];  // becomes the scatter cursor
  }
  __syncthreads();
  for (u32 e = beg + t; e < end; e += 256) {
    const uint2 it = part[e];
    const u32 nl = it.x >> 20;
    const u32 pos = beg + atomicAdd(&cnt[nl], 1u);
    srcw[pos] = make_uint2(it.x & 0xFFFFFu, it.y);
  }
}

// ---------------------------------------------------------------------------
// hs = fp16( dis .* (x @ W) )   fp32 math, W + x tile in LDS, fp16 store
// ---------------------------------------------------------------------------
template <int DOUT>
__global__ __launch_bounds__(256) void gemm_scale(
    const float* __restrict__ x, const float* __restrict__ W,
    const float* __restrict__ dis, __half* __restrict__ hs, int N) {
  static_assert(DOUT == 128 || DOUT == 64, "");
  constexpr int ROWS = 64;
  constexpr int CT = DOUT / 32;  // cols per thread
  constexpr int RT = 8;          // rows per thread
  __shared__ float wlds[128 * DOUT];
  __shared__ float xlds[ROWS * 128];

  const int tid = threadIdx.x;
  const int rowbase = blockIdx.x * ROWS;

  for (int i = tid * 4; i < 128 * DOUT; i += 256 * 4)
    *(float4*)(wlds + i) = *(const float4*)(W + i);
  for (int i = tid * 4; i < ROWS * 128; i += 256 * 4) {
    const int r = i >> 7, k = i & 127;
    const int row = rowbase + r;
    float4 v = make_float4(0.f, 0.f, 0.f, 0.f);
    if (row < N) v = *(const float4*)(x + (size_t)row * 128 + k);
    *(float4*)(xlds + i) = v;
  }
  __syncthreads();

  const int c0 = tid & 31;
  const int rg = tid >> 5;  // 0..7
  float acc[RT][CT];
#pragma unroll
  for (int r = 0; r < RT; ++r)
#pragma unroll
    for (int cc = 0; cc < CT; ++cc) acc[r][cc] = 0.f;

  for (int k = 0; k < 128; k += 4) {
    float4 xv[RT];
#pragma unroll
    for (int r = 0; r < RT; ++r)
      xv[r] = *(const float4*)(xlds + (rg * RT + r) * 128 + k);
#pragma unroll
    for (int kk = 0; kk < 4; ++kk) {
      float wv[CT];
#pragma unroll
      for (int cc = 0; cc < CT; ++cc)
        wv[cc] = wlds[(k + kk) * DOUT + c0 + 32 * cc];
#pragma unroll
      for (int r = 0; r < RT; ++r) {
        const float xk = (kk == 0) ? xv[r].x : (kk == 1) ? xv[r].y
                        : (kk == 2) ? xv[r].z : xv[r].w;
#pragma unroll
        for (int cc = 0; cc < CT; ++cc)
          acc[r][cc] = fmaf(xk, wv[cc], acc[r][cc]);
      }
    }
  }

#pragma unroll
  for (int r = 0; r < RT; ++r) {
    const int row = rowbase + rg * RT + r;
    if (row >= N) continue;
    const float d = dis[row];
#pragma unroll
    for (int cc = 0; cc < CT; ++cc)
      hs[(size_t)row * DOUT + c0 + 32 * cc] = __float2half(d * acc[r][cc]);
  }
}

// ---------------------------------------------------------------------------
// out[i] = dis[i]*(sum_e w_e*hs[src_e] + hs[i]) + b   (+ relu + dropout)
// one wave per destination node; hs rows are fp16 (256B / 128B per row)
// ---------------------------------------------------------------------------
template <int DOUT, bool ACT>
__global__ __launch_bounds__(256) void aggregate_k(
    const uint2* __restrict__ srcw, const u32* __restrict__ offsets,
    const float* __restrict__ dis, const __half* __restrict__ hs,
    const float* __restrict__ bias, float* __restrict__ out, int N,
    u32 ka, u32 kb) {
  const int lane = threadIdx.x & 63;
  const int wid = blockIdx.x * 4 + (threadIdx.x >> 6);
  if (wid >= N) return;
  const u32 beg = offsets[wid], end = offsets[wid + 1];

  if constexpr (DOUT == 128) {
    const int f0 = lane * 2;
    float ax = 0.f, ay = 0.f;
    u32 e = beg;
    for (; e + 4 <= end; e += 4) {
      const uint2 s0 = srcw[e + 0], s1 = srcw[e + 1], s2 = srcw[e + 2], s3 = srcw[e + 3];
      const __half2 h0 = *(const __half2*)(hs + (size_t)s0.x * 128 + f0);
      const __half2 h1 = *(const __half2*)(hs + (size_t)s1.x * 128 + f0);
      const __half2 h2 = *(const __half2*)(hs + (size_t)s2.x * 128 + f0);
      const __half2 h3 = *(const __half2*)(hs + (size_t)s3.x * 128 + f0);
      const float2 v0 = __half22float2(h0);
      const float2 v1 = __half22float2(h1);
      const float2 v2 = __half22float2(h2);
      const float2 v3 = __half22float2(h3);
      const float w0 = __uint_as_float(s0.y), w1 = __uint_as_float(s1.y);
      const float w2 = __uint_as_float(s2.y), w3 = __uint_as_float(s3.y);
      ax = fmaf(w0, v0.x, ax); ay = fmaf(w0, v0.y, ay);
      ax = fmaf(w1, v1.x, ax); ay = fmaf(w1, v1.y, ay);
      ax = fmaf(w2, v2.x, ax); ay = fmaf(w2, v2.y, ay);
      ax = fmaf(w3, v3.x, ax); ay = fmaf(w3, v3.y, ay);
    }
    for (; e < end; ++e) {
      const uint2 s0 = srcw[e];
      const float2 v0 = __half22float2(*(const __half2*)(hs + (size_t)s0.x * 128 + f0));
      const float w0 = __uint_as_float(s0.y);
      ax = fmaf(w0, v0.x, ax); ay = fmaf(w0, v0.y, ay);
    }
    const float d = dis[wid];
    const float2 sv = __half22float2(*(const __half2*)(hs + (size_t)wid * 128 + f0));
    float ox = d * (ax + sv.x) + bias[f0];
    float oy = d * (ay + sv.y) + bias[f0 + 1];
    if constexpr (ACT) {
      ox = fmaxf(ox, 0.f);
      oy = fmaxf(oy, 0.f);
      const u32 idx = (u32)wid * 128u + (u32)f0;
      ox = keep_elem(ka, kb, idx) ? 2.f * ox : 0.f;
      oy = keep_elem(ka, kb, idx + 1u) ? 2.f * oy : 0.f;
    }
    *(float2*)(out + (size_t)wid * 128 + f0) = make_float2(ox, oy);
  } else {
    float a = 0.f;
    u32 e = beg;
    for (; e + 4 <= end; e += 4) {
      const uint2 s0 = srcw[e + 0], s1 = srcw[e + 1], s2 = srcw[e + 2], s3 = srcw[e + 3];
      const float v0 = __half2float(hs[(size_t)s0.x * 64 + lane]);
      const float v1 = __half2float(hs[(size_t)s1.x * 64 + lane]);
      const float v2 = __half2float(hs[(size_t)s2.x * 64 + lane]);
      const float v3 = __half2float(hs[(size_t)s3.x * 64 + lane]);
      a = fmaf(__uint_as_float(s0.y), v0, a);
      a = fmaf(__uint_as_float(s1.y), v1, a);
      a = fmaf(__uint_as_float(s2.y), v2, a);
      a = fmaf(__uint_as_float(s3.y), v3, a);
    }
    for (; e < end; ++e) {
      const uint2 s0 = srcw[e];
      a = fmaf(__uint_as_float(s0.y), __half2float(hs[(size_t)s0.x * 64 + lane]), a);
    }
    const float d = dis[wid];
    const float o = d * (a + __half2float(hs[(size_t)wid * 64 + lane])) + bias[lane];
    out[(size_t)wid * 64 + lane] = o;
  }
}

// ---------------------------------------------------------------------------
extern "C" void kernel_launch(void* const* d_in, const int* in_sizes, int n_in,
                              void* d_out, int out_size, void* d_ws, size_t ws_size,
                              hipStream_t stream) {
  const float* x0 = (const float*)d_in[0];
  const u32* ei   = (const u32*)d_in[1];
  const float* ew = (const float*)d_in[2];
  const float* W1 = (const float*)d_in[3];
  const float* b1 = (const float*)d_in[4];
  const float* W2 = (const float*)d_in[5];
  const float* b2 = (const float*)d_in[6];
  const float* W3 = (const float*)d_in[7];
  const float* b3 = (const float*)d_in[8];

  const int N = in_sizes[0] / 128;
  const int E = in_sizes[2];
  const int P = (N + 127) >> 7;       // buckets of 128 dest nodes
  const int L = P * NB;               // part_hist length
  const int CHUNK = (E + NB - 1) / NB;

  char* p = (char*)d_ws;
  auto carve = [&](size_t bytes) -> char* {
    char* q = p;
    p += (bytes + 255) & ~(size_t)255;
    return q;
  };
  u32*    part_hist = (u32*)carve((size_t)L * 4);
  u32*    scanned   = (u32*)carve((size_t)(L + 1) * 4);
  u32*    node_offs = (u32*)carve((size_t)(N + 1) * 4);
  float*  dis       = (float*)carve((size_t)N * 4);
  u32*    flag      = (u32*)carve(256);
  uint2*  srcw      = (uint2*)carve((size_t)E * 8);
  __half* hs        = (__half*)carve((size_t)N * 128 * 2);
  float*  xbuf      = (float*)carve((size_t)N * 128 * 4);
  uint2*  part      = (uint2*)xbuf;  // alias: dead before aggregate L1 writes xbuf

  const int ggrid = (N + 63) / 64;
  const int agrid = (N + 3) / 4;
  const size_t lds_p = (size_t)P * 4;

  detect_kernel<<<1, 64, 0, stream>>>(ei, flag);
  partA_count<<<NB, 256, lds_p, stream>>>(ei, part_hist, E, P, CHUNK, flag);
  scan_kernel<<<1, 1024, 0, stream>>>(part_hist, scanned, L, node_offs, N, E);
  partC_scatter<<<NB, 256, lds_p, stream>>>(ei, ew, scanned, part, E, P, CHUNK, flag);
  bucket_sort<<<P, 256, 0, stream>>>(part, scanned, node_offs, dis, srcw, N);

  // layer 1
  gemm_scale<128><<<ggrid, 256, 0, stream>>>(x0, W1, dis, hs, N);
  aggregate_k<128, true><<<agrid, 256, 0, stream>>>(srcw, node_offs, dis, hs, b1, xbuf, N, DK1.a, DK1.b);
  // layer 2
  gemm_scale<128><<<ggrid, 256, 0, stream>>>(xbuf, W2, dis, hs, N);
  aggregate_k<128, true><<<agrid, 256, 0, stream>>>(srcw, node_offs, dis, hs, b2, xbuf, N, DK2.a, DK2.b);
  // layer 3
  gemm_scale<64><<<ggrid, 256, 0, stream>>>(xbuf, W3, dis, hs, N);
  aggregate_k<64, false><<<agrid, 256, 0, stream>>>(srcw, node_offs, dis, hs, b3, (float*)d_out, N, 0u, 0u);
}